// Round 2
// baseline (13303.098 us; speedup 1.0000x reference)
//
#include <hip/hip_runtime.h>

#define N_NODES 100000
#define N_EDGES 1600000
#define HDIM 128

// ---------------- CSR build ----------------

__global__ void hist_kernel(const int* __restrict__ ei, int* __restrict__ counts, int e) {
  int i = blockIdx.x * blockDim.x + threadIdx.x;
  if (i < e) atomicAdd(&counts[ei[e + i]], 1);  // dst row = ei[E..2E)
}

__global__ void scan1_kernel(const int* __restrict__ counts, int* __restrict__ offs,
                             int* __restrict__ bsums, int n) {
  __shared__ int sd[256];
  int t = threadIdx.x;
  int base = blockIdx.x * 1024 + t * 4;
  int v0 = (base + 0 < n) ? counts[base + 0] : 0;
  int v1 = (base + 1 < n) ? counts[base + 1] : 0;
  int v2 = (base + 2 < n) ? counts[base + 2] : 0;
  int v3 = (base + 3 < n) ? counts[base + 3] : 0;
  int s = v0 + v1 + v2 + v3;
  sd[t] = s;
  __syncthreads();
  for (int off = 1; off < 256; off <<= 1) {
    int x = (t >= off) ? sd[t - off] : 0;
    __syncthreads();
    sd[t] += x;
    __syncthreads();
  }
  int excl = sd[t] - s;
  if (t == 255) bsums[blockIdx.x] = sd[255];
  int r = excl;
  if (base + 0 < n) offs[base + 0] = r; r += v0;
  if (base + 1 < n) offs[base + 1] = r; r += v1;
  if (base + 2 < n) offs[base + 2] = r; r += v2;
  if (base + 3 < n) offs[base + 3] = r;
}

__global__ void scan2_kernel(int* __restrict__ bsums, int nb) {
  __shared__ int sd[128];
  int t = threadIdx.x;
  int v = (t < nb) ? bsums[t] : 0;
  sd[t] = v;
  __syncthreads();
  for (int off = 1; off < 128; off <<= 1) {
    int x = (t >= off) ? sd[t - off] : 0;
    __syncthreads();
    sd[t] += x;
    __syncthreads();
  }
  if (t < nb) bsums[t] = sd[t] - v;  // exclusive
}

__global__ void scan3_kernel(int* __restrict__ offs, const int* __restrict__ bsums, int n) {
  int i = blockIdx.x * blockDim.x + threadIdx.x;
  if (i < n) offs[i] += bsums[i >> 10];
}

__global__ void fill_kernel(const int* __restrict__ ei, const int* __restrict__ offs,
                            int* __restrict__ cursor, int* __restrict__ srcs, int e) {
  int i = blockIdx.x * blockDim.x + threadIdx.x;
  if (i < e) {
    int d = ei[e + i];
    int pos = offs[d] + atomicAdd(&cursor[d], 1);
    srcs[pos] = ei[i];  // src row = ei[0..E)
  }
}

// ---------------- aggregation: z[i] = h[i] + sum_{j in N_in(i)} h[j] ----------------

__global__ void aggregate_kernel(const float* __restrict__ h, const int* __restrict__ offs,
                                 const int* __restrict__ deg, const int* __restrict__ srcs,
                                 float* __restrict__ z, int n) {
  int wid = (int)((blockIdx.x * blockDim.x + threadIdx.x) >> 6);
  int lane = threadIdx.x & 63;
  if (wid >= n) return;
  int beg = offs[wid];
  int d = deg[wid];
  const int col = lane * 2;
  float2 acc = *(const float2*)(h + (size_t)wid * HDIM + col);
  int j = 0;
  for (; j + 4 <= d; j += 4) {
    int s0 = srcs[beg + j + 0];
    int s1 = srcs[beg + j + 1];
    int s2 = srcs[beg + j + 2];
    int s3 = srcs[beg + j + 3];
    float2 a0 = *(const float2*)(h + (size_t)s0 * HDIM + col);
    float2 a1 = *(const float2*)(h + (size_t)s1 * HDIM + col);
    float2 a2 = *(const float2*)(h + (size_t)s2 * HDIM + col);
    float2 a3 = *(const float2*)(h + (size_t)s3 * HDIM + col);
    acc.x += a0.x + a1.x + a2.x + a3.x;
    acc.y += a0.y + a1.y + a2.y + a3.y;
  }
  for (; j < d; ++j) {
    int s = srcs[beg + j];
    float2 a = *(const float2*)(h + (size_t)s * HDIM + col);
    acc.x += a.x;
    acc.y += a.y;
  }
  *(float2*)(z + (size_t)wid * HDIM + col) = acc;
}

// ---------------- fp32 GEMM: out = relu(A[N,128] @ W[128,128] + bias) ----------------
// 128x128 tile / 256 threads. Ws full in LDS (64KB, transposed+XOR-swizzled).
// A streamed as double-buffered 16-wide k-slices via global_load_lds (16KB).
// 80KB LDS total -> 2 blocks/CU -> 2 waves/SIMD.
// FUSE=1: epilogue computes out[i] = relu(...)@w_out + b_out (no 51MB h write).

template <int FUSE>
__global__ __launch_bounds__(256, 2)
void gemm_kernel(const float* __restrict__ A, const float* __restrict__ W,
                 const float* __restrict__ bias, float* __restrict__ out,
                 const float* __restrict__ wout, const float* __restrict__ bout, int n) {
  __shared__ float Ws[128 * 128];     // Ws[c*128 + (k ^ ((c>>3)<<2))]
  __shared__ float As[2][128 * 16];   // [r][chunk cc] holds global chunk cc ^ ((r>>3)&3)
  const int t = threadIdx.x;
  const int lane = t & 63;
  const int wv_ = t >> 6;             // wave id 0..3 (uniform)
  const int rowBase = blockIdx.x * 128;
  const int tc = t & 15;              // col group (8 cols)
  const int tr = t >> 4;              // row group (8 rows)

  // ---- issue A slice 0 loads first (latency hides under Ws staging) ----
  {
    #pragma unroll
    for (int c = 0; c < 2; ++c) {
      int r = c * 64 + wv_ * 16 + (lane >> 2);
      int gcc = (lane & 3) ^ ((r >> 3) & 3);
      const float* g = A + (size_t)(rowBase + r) * HDIM + 0 * 16 + gcc * 4;
      float* l = &As[0][c * 1024 + wv_ * 256];  // wave-uniform base; HW adds lane*16B
      __builtin_amdgcn_global_load_lds((const __attribute__((address_space(1))) void*)g,
                                       (__attribute__((address_space(3))) void*)l, 16, 0, 0);
    }
  }

  // ---- stage W (transpose + swizzle); W[k][c] row-major in global ----
  #pragma unroll
  for (int it = 0; it < 16; ++it) {
    int idx = (it * 256 + t) * 4;
    int k = idx >> 7;
    int c0 = idx & 127;
    float4 v = *(const float4*)(W + idx);
    Ws[(c0 + 0) * 128 + (k ^ (((c0 + 0) >> 3) << 2))] = v.x;
    Ws[(c0 + 1) * 128 + (k ^ (((c0 + 1) >> 3) << 2))] = v.y;
    Ws[(c0 + 2) * 128 + (k ^ (((c0 + 2) >> 3) << 2))] = v.z;
    Ws[(c0 + 3) * 128 + (k ^ (((c0 + 3) >> 3) << 2))] = v.w;
  }

  float bv[8];
  #pragma unroll
  for (int j = 0; j < 8; ++j) bv[j] = bias[tc * 8 + j];

  float acc[8][8];
  #pragma unroll
  for (int i = 0; i < 8; ++i)
    #pragma unroll
    for (int j = 0; j < 8; ++j) acc[i][j] = 0.f;

  __syncthreads();  // drains vmcnt (slice 0) + lgkm (Ws)

  // ---- main loop: 8 k-slices of 16, double-buffered ----
  #pragma unroll
  for (int s = 0; s < 8; ++s) {
    const int buf = s & 1;
    if (s < 7) {
      #pragma unroll
      for (int c = 0; c < 2; ++c) {
        int r = c * 64 + wv_ * 16 + (lane >> 2);
        int gcc = (lane & 3) ^ ((r >> 3) & 3);
        const float* g = A + (size_t)(rowBase + r) * HDIM + (s + 1) * 16 + gcc * 4;
        float* l = &As[buf ^ 1][c * 1024 + wv_ * 256];
        __builtin_amdgcn_global_load_lds((const __attribute__((address_space(1))) void*)g,
                                         (__attribute__((address_space(3))) void*)l, 16, 0, 0);
      }
    }
    #pragma unroll
    for (int kc = 0; kc < 4; ++kc) {
      float4 a[8], wv4[8];
      const int ka = (kc ^ (tr & 3)) << 2;
      const int kw = (s * 16 + kc * 4) ^ (tc << 2);
      #pragma unroll
      for (int i = 0; i < 8; ++i) a[i] = *(const float4*)&As[buf][(tr * 8 + i) * 16 + ka];
      #pragma unroll
      for (int j = 0; j < 8; ++j) wv4[j] = *(const float4*)&Ws[(tc * 8 + j) * 128 + kw];
      #pragma unroll
      for (int i = 0; i < 8; ++i)
        #pragma unroll
        for (int j = 0; j < 8; ++j)
          acc[i][j] += a[i].x * wv4[j].x + a[i].y * wv4[j].y +
                       a[i].z * wv4[j].z + a[i].w * wv4[j].w;
    }
    __syncthreads();  // stage(s+1) landed; everyone done reading buf
  }

  if (FUSE) {
    // out[r] = sum_c relu(acc + bias)[r][c] * wout[c] + bout
    float wvo[8];
    #pragma unroll
    for (int j = 0; j < 8; ++j) wvo[j] = wout[tc * 8 + j];
    float* red = (float*)As;  // 128 rows x 16 groups = 2048 floats
    #pragma unroll
    for (int i = 0; i < 8; ++i) {
      float si = 0.f;
      #pragma unroll
      for (int j = 0; j < 8; ++j) si += fmaxf(acc[i][j] + bv[j], 0.f) * wvo[j];
      red[(tr * 8 + i) * 16 + tc] = si;
    }
    __syncthreads();
    if (t < 128) {
      int gr = rowBase + t;
      if (gr < n) {
        float s = 0.f;
        #pragma unroll
        for (int g = 0; g < 16; ++g) s += red[t * 16 + g];
        out[gr] = s + bout[0];
      }
    }
  } else {
    #pragma unroll
    for (int i = 0; i < 8; ++i) {
      int gr = rowBase + tr * 8 + i;
      if (gr < n) {
        float4 o0, o1;
        o0.x = fmaxf(acc[i][0] + bv[0], 0.f);
        o0.y = fmaxf(acc[i][1] + bv[1], 0.f);
        o0.z = fmaxf(acc[i][2] + bv[2], 0.f);
        o0.w = fmaxf(acc[i][3] + bv[3], 0.f);
        o1.x = fmaxf(acc[i][4] + bv[4], 0.f);
        o1.y = fmaxf(acc[i][5] + bv[5], 0.f);
        o1.z = fmaxf(acc[i][6] + bv[6], 0.f);
        o1.w = fmaxf(acc[i][7] + bv[7], 0.f);
        *(float4*)(out + (size_t)gr * HDIM + tc * 8) = o0;
        *(float4*)(out + (size_t)gr * HDIM + tc * 8 + 4) = o1;
      }
    }
  }
}

// ---------------- launch ----------------

extern "C" void kernel_launch(void* const* d_in, const int* in_sizes, int n_in,
                              void* d_out, int out_size, void* d_ws, size_t ws_size,
                              hipStream_t stream) {
  const float* x = (const float*)d_in[0];
  const int* ei = (const int*)d_in[1];
  const float* w1[3] = {(const float*)d_in[2], (const float*)d_in[6], (const float*)d_in[10]};
  const float* b1[3] = {(const float*)d_in[3], (const float*)d_in[7], (const float*)d_in[11]};
  const float* w2[3] = {(const float*)d_in[4], (const float*)d_in[8], (const float*)d_in[12]};
  const float* b2[3] = {(const float*)d_in[5], (const float*)d_in[9], (const float*)d_in[13]};
  const float* wout = (const float*)d_in[14];
  const float* bout = (const float*)d_in[15];
  float* out = (float*)d_out;

  char* ws = (char*)d_ws;
  size_t off = 0;
  float* B0 = (float*)(ws + off); off += (size_t)N_NODES * HDIM * 4;
  float* B1 = (float*)(ws + off); off += (size_t)N_NODES * HDIM * 4;
  float* B2 = (float*)(ws + off); off += (size_t)N_NODES * HDIM * 4;
  int* offs   = (int*)(ws + off); off += (size_t)N_NODES * 4;
  int* counts = (int*)(ws + off); off += (size_t)N_NODES * 4;
  int* bsums  = (int*)(ws + off); off += 1024;
  int* srcs   = (int*)(ws + off); off += (size_t)N_EDGES * 4;

  // ---- CSR build (reused by all 3 layers) ----
  hipMemsetAsync(counts, 0, (size_t)N_NODES * 4, stream);
  hist_kernel<<<(N_EDGES + 255) / 256, 256, 0, stream>>>(ei, counts, N_EDGES);
  int nb = (N_NODES + 1023) / 1024;  // 98
  scan1_kernel<<<nb, 256, 0, stream>>>(counts, offs, bsums, N_NODES);
  scan2_kernel<<<1, 128, 0, stream>>>(bsums, nb);
  scan3_kernel<<<(N_NODES + 255) / 256, 256, 0, stream>>>(offs, bsums, N_NODES);
  hipMemsetAsync(counts, 0, (size_t)N_NODES * 4, stream);
  fill_kernel<<<(N_EDGES + 255) / 256, 256, 0, stream>>>(ei, offs, counts, srcs, N_EDGES);

  int aggGrid = (N_NODES * 64 + 255) / 256;   // one wave per node
  int gemmGrid = (N_NODES + 127) / 128;       // 782

  // layer 1
  aggregate_kernel<<<aggGrid, 256, 0, stream>>>(x, offs, counts, srcs, B0, N_NODES);
  gemm_kernel<0><<<gemmGrid, 256, 0, stream>>>(B0, w1[0], b1[0], B1, nullptr, nullptr, N_NODES);
  gemm_kernel<0><<<gemmGrid, 256, 0, stream>>>(B1, w2[0], b2[0], B0, nullptr, nullptr, N_NODES);
  // layer 2
  aggregate_kernel<<<aggGrid, 256, 0, stream>>>(B0, offs, counts, srcs, B1, N_NODES);
  gemm_kernel<0><<<gemmGrid, 256, 0, stream>>>(B1, w1[1], b1[1], B2, nullptr, nullptr, N_NODES);
  gemm_kernel<0><<<gemmGrid, 256, 0, stream>>>(B2, w2[1], b2[1], B1, nullptr, nullptr, N_NODES);
  // layer 3
  aggregate_kernel<<<aggGrid, 256, 0, stream>>>(B1, offs, counts, srcs, B2, N_NODES);
  gemm_kernel<0><<<gemmGrid, 256, 0, stream>>>(B2, w1[2], b1[2], B0, nullptr, nullptr, N_NODES);
  // last GEMM fused with output projection (never materializes h3)
  gemm_kernel<1><<<gemmGrid, 256, 0, stream>>>(B0, w2[2], b2[2], out, wout, bout, N_NODES);
}

// Round 3
// 601.161 us; speedup vs baseline: 22.1290x; 22.1290x over previous
//
#include <hip/hip_runtime.h>

#define N_NODES 100000
#define N_EDGES 1600000

typedef _Float16 f16;
typedef _Float16 f16x2 __attribute__((ext_vector_type(2)));
typedef _Float16 f16x8 __attribute__((ext_vector_type(8)));
typedef float f32x4 __attribute__((ext_vector_type(4)));

// ---------------- CSR build ----------------

__global__ void hist_kernel(const int* __restrict__ ei, int* __restrict__ counts, int e) {
  int i = blockIdx.x * blockDim.x + threadIdx.x;
  if (i < e) atomicAdd(&counts[ei[e + i]], 1);  // dst row = ei[E..2E)
}

__global__ void scan1_kernel(const int* __restrict__ counts, int* __restrict__ offs,
                             int* __restrict__ bsums, int n) {
  __shared__ int sd[256];
  int t = threadIdx.x;
  int base = blockIdx.x * 1024 + t * 4;
  int v0 = (base + 0 < n) ? counts[base + 0] : 0;
  int v1 = (base + 1 < n) ? counts[base + 1] : 0;
  int v2 = (base + 2 < n) ? counts[base + 2] : 0;
  int v3 = (base + 3 < n) ? counts[base + 3] : 0;
  int s = v0 + v1 + v2 + v3;
  sd[t] = s;
  __syncthreads();
  for (int off = 1; off < 256; off <<= 1) {
    int x = (t >= off) ? sd[t - off] : 0;
    __syncthreads();
    sd[t] += x;
    __syncthreads();
  }
  int excl = sd[t] - s;
  if (t == 255) bsums[blockIdx.x] = sd[255];
  int r = excl;
  if (base + 0 < n) offs[base + 0] = r; r += v0;
  if (base + 1 < n) offs[base + 1] = r; r += v1;
  if (base + 2 < n) offs[base + 2] = r; r += v2;
  if (base + 3 < n) offs[base + 3] = r;
}

__global__ void scan2_kernel(int* __restrict__ bsums, int nb) {
  __shared__ int sd[128];
  int t = threadIdx.x;
  int v = (t < nb) ? bsums[t] : 0;
  sd[t] = v;
  __syncthreads();
  for (int off = 1; off < 128; off <<= 1) {
    int x = (t >= off) ? sd[t - off] : 0;
    __syncthreads();
    sd[t] += x;
    __syncthreads();
  }
  if (t < nb) bsums[t] = sd[t] - v;  // exclusive
}

__global__ void scan3_kernel(int* __restrict__ offs, const int* __restrict__ bsums, int n) {
  int i = blockIdx.x * blockDim.x + threadIdx.x;
  if (i < n) offs[i] += bsums[i >> 10];
}

__global__ void fill_kernel(const int* __restrict__ ei, const int* __restrict__ offs,
                            int* __restrict__ cursor, int* __restrict__ srcs, int e) {
  int i = blockIdx.x * blockDim.x + threadIdx.x;
  if (i < e) {
    int d = ei[e + i];
    int pos = offs[d] + atomicAdd(&cursor[d], 1);
    srcs[pos] = ei[i];  // src row = ei[0..E)
  }
}

// ---------------- fp32 -> fp16 convert (x) ----------------

__global__ void cvt_kernel(const float* __restrict__ x, f16* __restrict__ y) {
  int i = (blockIdx.x * 256 + threadIdx.x) * 8;
  float4 a = *(const float4*)(x + i);
  float4 b = *(const float4*)(x + i + 4);
  f16x8 v = {(f16)a.x, (f16)a.y, (f16)a.z, (f16)a.w,
             (f16)b.x, (f16)b.y, (f16)b.z, (f16)b.w};
  *(f16x8*)(y + i) = v;
}

// ---------------- weight prep: Wt[c][k] = (f16)W[k][c], chunk-XOR pre-swizzled ----------------
// Wt_g[c*128 + kc*8 + j] = W[((kc ^ (c&7))*8 + j)*128 + c]   (kc = 16B-chunk index 0..15)

__global__ void wprep_kernel(const float* __restrict__ W, f16* __restrict__ Wt) {
  int t = blockIdx.x * 256 + threadIdx.x;  // 0..16383
  int c = t >> 7;
  int i = t & 127;
  int kc = i >> 3, j = i & 7;
  int k = ((kc ^ (c & 7)) << 3) + j;
  Wt[t] = (f16)W[k * 128 + c];
}

// ---------------- aggregation: z[i] = h[i] + sum_{j in N_in(i)} h[j]  (fp16 io, fp32 acc) ----------------

__global__ void aggregate_kernel(const f16* __restrict__ h, const int* __restrict__ offs,
                                 const int* __restrict__ deg, const int* __restrict__ srcs,
                                 f16* __restrict__ z, int n) {
  int wid = (int)((blockIdx.x * blockDim.x + threadIdx.x) >> 6);
  int lane = threadIdx.x & 63;
  if (wid >= n) return;
  int beg = offs[wid];
  int d = deg[wid];
  const int col = lane * 2;
  f16x2 h0 = *(const f16x2*)(h + (size_t)wid * 128 + col);
  float ax = (float)h0.x, ay = (float)h0.y;
  int j = 0;
  for (; j + 4 <= d; j += 4) {
    int s0 = srcs[beg + j + 0];
    int s1 = srcs[beg + j + 1];
    int s2 = srcs[beg + j + 2];
    int s3 = srcs[beg + j + 3];
    f16x2 a0 = *(const f16x2*)(h + (size_t)s0 * 128 + col);
    f16x2 a1 = *(const f16x2*)(h + (size_t)s1 * 128 + col);
    f16x2 a2 = *(const f16x2*)(h + (size_t)s2 * 128 + col);
    f16x2 a3 = *(const f16x2*)(h + (size_t)s3 * 128 + col);
    ax += (float)a0.x + (float)a1.x + (float)a2.x + (float)a3.x;
    ay += (float)a0.y + (float)a1.y + (float)a2.y + (float)a3.y;
  }
  for (; j < d; ++j) {
    int s = srcs[beg + j];
    f16x2 a = *(const f16x2*)(h + (size_t)s * 128 + col);
    ax += (float)a.x;
    ay += (float)a.y;
  }
  f16x2 o = {(f16)ax, (f16)ay};
  *(f16x2*)(z + (size_t)wid * 128 + col) = o;
}

// ---------------- fp16 MFMA GEMM: out = relu(A[N,128] @ W[128,128] + bias) ----------------
// 128x128 tile / 256 threads (4 waves, 2x2 wave grid of 64x64 wave-tiles).
// A tile (32KB) + Wt tile (32KB) in LDS -> 2 blocks/CU.
// LDS chunk-XOR swizzle: LDS[r][chunk c] holds global chunk (c ^ (r&7)) -> 2-way-free ds_read_b128.
// FUSE=1: epilogue computes out[i] = relu(.)@w_out + b_out (fp32), skipping the h write.

template <int FUSE>
__global__ __launch_bounds__(256, 2)
void gemm_kernel(const f16* __restrict__ A, const f16* __restrict__ Wt,
                 const float* __restrict__ bias, void* __restrict__ outv,
                 const float* __restrict__ wout, const float* __restrict__ bout, int n) {
  __shared__ f16 Az[128 * 128];  // 32KB
  __shared__ f16 Ws[128 * 128];  // 32KB
  const int t = threadIdx.x;
  const int lane = t & 63;
  const int w = t >> 6;
  const int rowBase = blockIdx.x * 128;

  // ---- reg-stage A (chunk-swizzled ds_write) + Wt (pre-swizzled, linear) ----
  {
    const char* Ab = (const char*)(A + (size_t)rowBase * 128);
    const char* Wb = (const char*)Wt;
    float4 va[8], vw[8];
    #pragma unroll
    for (int i = 0; i < 8; ++i) {
      int s = w * 512 + i * 64 + lane;
      va[i] = *(const float4*)(Ab + s * 16);
      vw[i] = *(const float4*)(Wb + s * 16);
    }
    #pragma unroll
    for (int i = 0; i < 8; ++i) {
      int s = w * 512 + i * 64 + lane;
      int r = s >> 4, c = s & 15;
      *(float4*)((char*)Az + r * 256 + ((c ^ (r & 7)) << 4)) = va[i];
      *(float4*)((char*)Ws + s * 16) = vw[i];
    }
  }
  __syncthreads();

  const int wr = w >> 1, wc = w & 1;
  const int ls = lane & 15, lg = lane >> 4;

  f32x4 acc[4][4];
  #pragma unroll
  for (int m = 0; m < 4; ++m)
    #pragma unroll
    for (int nn = 0; nn < 4; ++nn)
      acc[m][nn] = (f32x4){0.f, 0.f, 0.f, 0.f};

  #pragma unroll
  for (int ks = 0; ks < 4; ++ks) {
    f16x8 a[4], b[4];
    #pragma unroll
    for (int m = 0; m < 4; ++m) {
      int r = wr * 64 + m * 16 + ls;
      int ch = (ks * 4 + lg) ^ (r & 7);
      a[m] = *(const f16x8*)((const char*)Az + r * 256 + (ch << 4));
    }
    #pragma unroll
    for (int nn = 0; nn < 4; ++nn) {
      int c = wc * 64 + nn * 16 + ls;
      int ch = (ks * 4 + lg) ^ (c & 7);
      b[nn] = *(const f16x8*)((const char*)Ws + c * 256 + (ch << 4));
    }
    #pragma unroll
    for (int m = 0; m < 4; ++m)
      #pragma unroll
      for (int nn = 0; nn < 4; ++nn)
        acc[m][nn] = __builtin_amdgcn_mfma_f32_16x16x32_f16(a[m], b[nn], acc[m][nn], 0, 0, 0);
  }

  if (FUSE) {
    // out[r] = sum_c relu(acc + bias)[r][c] * wout[c] + bout   (h3 never stored)
    float bv[4], wv[4];
    #pragma unroll
    for (int nn = 0; nn < 4; ++nn) {
      bv[nn] = bias[wc * 64 + nn * 16 + ls];
      wv[nn] = wout[wc * 64 + nn * 16 + ls];
    }
    __syncthreads();  // everyone done reading Az before reuse
    float* red = (float*)Az;  // [128][33] padded
    #pragma unroll
    for (int m = 0; m < 4; ++m)
      #pragma unroll
      for (int i = 0; i < 4; ++i) {
        int rl = wr * 64 + m * 16 + lg * 4 + i;
        float s = 0.f;
        #pragma unroll
        for (int nn = 0; nn < 4; ++nn)
          s += fmaxf(acc[m][nn][i] + bv[nn], 0.f) * wv[nn];
        red[rl * 33 + wc * 16 + ls] = s;
      }
    __syncthreads();
    if (t < 128) {
      int gr = rowBase + t;
      if (gr < n) {
        float s = 0.f;
        #pragma unroll
        for (int g = 0; g < 32; ++g) s += red[t * 33 + g];
        ((float*)outv)[gr] = s + bout[0];
      }
    }
  } else {
    float bv[4];
    #pragma unroll
    for (int nn = 0; nn < 4; ++nn) bv[nn] = bias[wc * 64 + nn * 16 + ls];
    f16* out = (f16*)outv;
    #pragma unroll
    for (int m = 0; m < 4; ++m)
      #pragma unroll
      for (int i = 0; i < 4; ++i) {
        int gr = rowBase + wr * 64 + m * 16 + lg * 4 + i;
        if (gr < n) {
          f16* orow = out + (size_t)gr * 128 + wc * 64 + ls;
          #pragma unroll
          for (int nn = 0; nn < 4; ++nn)
            orow[nn * 16] = (f16)fmaxf(acc[m][nn][i] + bv[nn], 0.f);
        }
      }
  }
}

// ---------------- launch ----------------

extern "C" void kernel_launch(void* const* d_in, const int* in_sizes, int n_in,
                              void* d_out, int out_size, void* d_ws, size_t ws_size,
                              hipStream_t stream) {
  const float* x = (const float*)d_in[0];
  const int* ei = (const int*)d_in[1];
  const float* w1[3] = {(const float*)d_in[2], (const float*)d_in[6], (const float*)d_in[10]};
  const float* b1[3] = {(const float*)d_in[3], (const float*)d_in[7], (const float*)d_in[11]};
  const float* w2[3] = {(const float*)d_in[4], (const float*)d_in[8], (const float*)d_in[12]};
  const float* b2[3] = {(const float*)d_in[5], (const float*)d_in[9], (const float*)d_in[13]};
  const float* wout = (const float*)d_in[14];
  const float* bout = (const float*)d_in[15];
  float* out = (float*)d_out;

  char* ws = (char*)d_ws;
  size_t off = 0;
  f16* B0  = (f16*)(ws + off); off += (size_t)N_NODES * 128 * 2;
  f16* B1  = (f16*)(ws + off); off += (size_t)N_NODES * 128 * 2;
  f16* B2  = (f16*)(ws + off); off += (size_t)N_NODES * 128 * 2;
  f16* x16 = (f16*)(ws + off); off += (size_t)N_NODES * 128 * 2;
  f16* Wt[6];
  for (int i = 0; i < 6; ++i) { Wt[i] = (f16*)(ws + off); off += 128 * 128 * 2; }
  int* offs   = (int*)(ws + off); off += (size_t)N_NODES * 4;
  int* counts = (int*)(ws + off); off += (size_t)N_NODES * 4;
  int* bsums  = (int*)(ws + off); off += 1024;
  int* srcs   = (int*)(ws + off); off += (size_t)N_EDGES * 4;

  // ---- CSR build (reused by all 3 layers) ----
  hipMemsetAsync(counts, 0, (size_t)N_NODES * 4, stream);
  hist_kernel<<<(N_EDGES + 255) / 256, 256, 0, stream>>>(ei, counts, N_EDGES);
  int nb = (N_NODES + 1023) / 1024;  // 98
  scan1_kernel<<<nb, 256, 0, stream>>>(counts, offs, bsums, N_NODES);
  scan2_kernel<<<1, 128, 0, stream>>>(bsums, nb);
  scan3_kernel<<<(N_NODES + 255) / 256, 256, 0, stream>>>(offs, bsums, N_NODES);
  hipMemsetAsync(counts, 0, (size_t)N_NODES * 4, stream);
  fill_kernel<<<(N_EDGES + 255) / 256, 256, 0, stream>>>(ei, offs, counts, srcs, N_EDGES);

  // ---- input/weight conversion ----
  cvt_kernel<<<(N_NODES * 128) / (256 * 8), 256, 0, stream>>>(x, x16);  // 6250 blocks
  const float* wsrc[6] = {w1[0], w2[0], w1[1], w2[1], w1[2], w2[2]};
  for (int i = 0; i < 6; ++i)
    wprep_kernel<<<64, 256, 0, stream>>>(wsrc[i], Wt[i]);

  int aggGrid = (N_NODES * 64) / 256;          // 25000 (one wave per node)
  int gemmGrid = (N_NODES + 127) / 128;        // 782

  // layer 1
  aggregate_kernel<<<aggGrid, 256, 0, stream>>>(x16, offs, counts, srcs, B0, N_NODES);
  gemm_kernel<0><<<gemmGrid, 256, 0, stream>>>(B0, Wt[0], b1[0], B1, nullptr, nullptr, N_NODES);
  gemm_kernel<0><<<gemmGrid, 256, 0, stream>>>(B1, Wt[1], b2[0], B0, nullptr, nullptr, N_NODES);
  // layer 2
  aggregate_kernel<<<aggGrid, 256, 0, stream>>>(B0, offs, counts, srcs, B1, N_NODES);
  gemm_kernel<0><<<gemmGrid, 256, 0, stream>>>(B1, Wt[2], b1[1], B2, nullptr, nullptr, N_NODES);
  gemm_kernel<0><<<gemmGrid, 256, 0, stream>>>(B2, Wt[3], b2[1], B1, nullptr, nullptr, N_NODES);
  // layer 3
  aggregate_kernel<<<aggGrid, 256, 0, stream>>>(B1, offs, counts, srcs, B2, N_NODES);
  gemm_kernel<0><<<gemmGrid, 256, 0, stream>>>(B2, Wt[4], b1[2], B0, nullptr, nullptr, N_NODES);
  // last GEMM fused with output projection (h3 never materialized)
  gemm_kernel<1><<<gemmGrid, 256, 0, stream>>>(B0, Wt[5], b2[2], out, wout, bout, N_NODES);
}

// Round 4
// 513.283 us; speedup vs baseline: 25.9176x; 1.1712x over previous
//
#include <hip/hip_runtime.h>

#define N_NODES 100000
#define N_EDGES 1600000
#define SLICE 12500     // N_NODES/8 dst-slice per group
#define FCHUNK 16384    // edges per fill chunk

typedef _Float16 f16;
typedef _Float16 f16x2 __attribute__((ext_vector_type(2)));
typedef _Float16 f16x8 __attribute__((ext_vector_type(8)));
typedef float f32x4 __attribute__((ext_vector_type(4)));

// ---------------- CSR build ----------------
// hist + per-edge rank in one pass (rank write is coalesced)
__global__ void hist_rank_kernel(const int* __restrict__ ei, int* __restrict__ counts,
                                 int* __restrict__ rank, int e) {
  int i = blockIdx.x * blockDim.x + threadIdx.x;
  if (i < e) rank[i] = atomicAdd(&counts[ei[e + i]], 1);
}

__global__ void scan1_kernel(const int* __restrict__ counts, int* __restrict__ offs,
                             int* __restrict__ bsums, int n) {
  __shared__ int sd[256];
  int t = threadIdx.x;
  int base = blockIdx.x * 1024 + t * 4;
  int v0 = (base + 0 < n) ? counts[base + 0] : 0;
  int v1 = (base + 1 < n) ? counts[base + 1] : 0;
  int v2 = (base + 2 < n) ? counts[base + 2] : 0;
  int v3 = (base + 3 < n) ? counts[base + 3] : 0;
  int s = v0 + v1 + v2 + v3;
  sd[t] = s;
  __syncthreads();
  for (int off = 1; off < 256; off <<= 1) {
    int x = (t >= off) ? sd[t - off] : 0;
    __syncthreads();
    sd[t] += x;
    __syncthreads();
  }
  int excl = sd[t] - s;
  if (t == 255) bsums[blockIdx.x] = sd[255];
  int r = excl;
  if (base + 0 < n) offs[base + 0] = r; r += v0;
  if (base + 1 < n) offs[base + 1] = r; r += v1;
  if (base + 2 < n) offs[base + 2] = r; r += v2;
  if (base + 3 < n) offs[base + 3] = r;
}

__global__ void scan2_kernel(int* __restrict__ bsums, int nb) {
  __shared__ int sd[128];
  int t = threadIdx.x;
  int v = (t < nb) ? bsums[t] : 0;
  sd[t] = v;
  __syncthreads();
  for (int off = 1; off < 128; off <<= 1) {
    int x = (t >= off) ? sd[t - off] : 0;
    __syncthreads();
    sd[t] += x;
    __syncthreads();
  }
  if (t < nb) bsums[t] = sd[t] - v;  // exclusive
}

__global__ void scan3_kernel(int* __restrict__ offs, const int* __restrict__ bsums, int n) {
  int i = blockIdx.x * blockDim.x + threadIdx.x;
  if (i < n) offs[i] += bsums[i >> 10];
}

// atomic-free, dst-sliced scatter: group g = blockIdx&7 owns dst in [g*SLICE,(g+1)*SLICE)
// -> each group's writes span only ~800KB of srcs (single-L2-owner lines).
__global__ void fill_sliced_kernel(const int* __restrict__ ei, const int* __restrict__ offs,
                                   const int* __restrict__ rank, int* __restrict__ srcs, int e) {
  int grp = blockIdx.x & 7;
  int chunk = blockIdx.x >> 3;
  int lo = grp * SLICE;
  int hi = lo + SLICE;  // last slice: 100000 exactly
  int base = chunk * FCHUNK;
  #pragma unroll 4
  for (int k = threadIdx.x; k < FCHUNK; k += 256) {
    int i = base + k;
    if (i < e) {
      int d = ei[e + i];
      if (d >= lo && d < hi) srcs[offs[d] + rank[i]] = ei[i];
    }
  }
}

// ---------------- fp32 -> fp16 convert (x) ----------------
__global__ void cvt_kernel(const float* __restrict__ x, f16* __restrict__ y) {
  int i = (blockIdx.x * 256 + threadIdx.x) * 8;
  float4 a = *(const float4*)(x + i);
  float4 b = *(const float4*)(x + i + 4);
  f16x8 v = {(f16)a.x, (f16)a.y, (f16)a.z, (f16)a.w,
             (f16)b.x, (f16)b.y, (f16)b.z, (f16)b.w};
  *(f16x8*)(y + i) = v;
}

// ---------------- weight prep (all 6 in one launch) ----------------
// Wt[c*128 + kc*8 + j] = (f16)W[((kc ^ (c&7))*8 + j)*128 + c]
struct WPack { const float* w[6]; f16* o[6]; };
__global__ void wprep_all_kernel(WPack p) {
  int wi = blockIdx.x >> 6;                       // 0..5
  int t = (blockIdx.x & 63) * 256 + threadIdx.x;  // 0..16383
  int c = t >> 7;
  int i = t & 127;
  int kc = i >> 3, j = i & 7;
  int k = ((kc ^ (c & 7)) << 3) + j;
  p.o[wi][t] = (f16)p.w[wi][k * 128 + c];
}

// ---------------- aggregation: z[i] = h[i] + sum_{j in N_in(i)} h[j] ----------------
__global__ void aggregate_kernel(const f16* __restrict__ h, const int* __restrict__ offs,
                                 const int* __restrict__ deg, const int* __restrict__ srcs,
                                 f16* __restrict__ z, int n) {
  int wid = (int)((blockIdx.x * blockDim.x + threadIdx.x) >> 6);
  int lane = threadIdx.x & 63;
  if (wid >= n) return;
  int beg = offs[wid];
  int d = deg[wid];
  const int col = lane * 2;
  f16x2 h0 = *(const f16x2*)(h + (size_t)wid * 128 + col);
  float ax = (float)h0.x, ay = (float)h0.y;
  for (int base = 0; base < d; base += 64) {
    int cnt = min(64, d - base);
    int sv = (base + lane < d) ? srcs[beg + base + lane] : 0;  // one coalesced load / 64 edges
    int j = 0;
    for (; j + 4 <= cnt; j += 4) {
      int s0 = __shfl(sv, j + 0);
      int s1 = __shfl(sv, j + 1);
      int s2 = __shfl(sv, j + 2);
      int s3 = __shfl(sv, j + 3);
      f16x2 a0 = *(const f16x2*)(h + (size_t)s0 * 128 + col);
      f16x2 a1 = *(const f16x2*)(h + (size_t)s1 * 128 + col);
      f16x2 a2 = *(const f16x2*)(h + (size_t)s2 * 128 + col);
      f16x2 a3 = *(const f16x2*)(h + (size_t)s3 * 128 + col);
      ax += (float)a0.x + (float)a1.x + (float)a2.x + (float)a3.x;
      ay += (float)a0.y + (float)a1.y + (float)a2.y + (float)a3.y;
    }
    for (; j < cnt; ++j) {
      int s = __shfl(sv, j);
      f16x2 a = *(const f16x2*)(h + (size_t)s * 128 + col);
      ax += (float)a.x;
      ay += (float)a.y;
    }
  }
  f16x2 o = {(f16)ax, (f16)ay};
  *(f16x2*)(z + (size_t)wid * 128 + col) = o;
}

// ---------------- fused GIN layer: h2 = relu(relu(A@W1+b1)@W2+b2) ----------------
// 128x128 tile / 256 threads (2x2 waves of 64x64). A + W1 + W2 in LDS = 96KB.
// h1 redistributed through Az between phases. FUSE=1: out[i]=h2[i]@w_out+b_out (fp32).
template <int FUSE>
__global__ __launch_bounds__(256, 1)
void layer_kernel(const f16* __restrict__ A, const f16* __restrict__ W1t,
                  const f16* __restrict__ W2t,
                  const float* __restrict__ bias1, const float* __restrict__ bias2,
                  void* __restrict__ outv,
                  const float* __restrict__ wout, const float* __restrict__ bout, int n) {
  __shared__ f16 Az[128 * 128];   // 32KB: A, then h1 (chunk-XOR swizzled)
  __shared__ f16 W1s[128 * 128];  // 32KB (pre-swizzled in global)
  __shared__ f16 W2s[128 * 128];  // 32KB
  const int t = threadIdx.x;
  const int lane = t & 63;
  const int w = t >> 6;
  const int rowBase = blockIdx.x * 128;

  // ---- stage A (swizzled ds_write) + W1 + W2 (linear) ----
  {
    const char* Ab = (const char*)(A + (size_t)rowBase * 128);
    float4 va[8], v1[8], v2[8];
    #pragma unroll
    for (int i = 0; i < 8; ++i) {
      int s = w * 512 + i * 64 + lane;
      va[i] = *(const float4*)(Ab + s * 16);
      v1[i] = *(const float4*)((const char*)W1t + s * 16);
      v2[i] = *(const float4*)((const char*)W2t + s * 16);
    }
    #pragma unroll
    for (int i = 0; i < 8; ++i) {
      int s = w * 512 + i * 64 + lane;
      int r = s >> 4, c = s & 15;
      *(float4*)((char*)Az + r * 256 + ((c ^ (r & 7)) << 4)) = va[i];
      *(float4*)((char*)W1s + s * 16) = v1[i];
      *(float4*)((char*)W2s + s * 16) = v2[i];
    }
  }
  __syncthreads();

  const int wr = w >> 1, wc = w & 1;
  const int ls = lane & 15, lg = lane >> 4;

  f32x4 acc[4][4];
  #pragma unroll
  for (int m = 0; m < 4; ++m)
    #pragma unroll
    for (int nn = 0; nn < 4; ++nn)
      acc[m][nn] = (f32x4){0.f, 0.f, 0.f, 0.f};

  // ---- phase 1: h1 = A @ W1 ----
  #pragma unroll
  for (int ks = 0; ks < 4; ++ks) {
    f16x8 a[4], b[4];
    #pragma unroll
    for (int m = 0; m < 4; ++m) {
      int r = wr * 64 + m * 16 + ls;
      int ch = (ks * 4 + lg) ^ (r & 7);
      a[m] = *(const f16x8*)((const char*)Az + r * 256 + (ch << 4));
    }
    #pragma unroll
    for (int nn = 0; nn < 4; ++nn) {
      int c = wc * 64 + nn * 16 + ls;
      int ch = (ks * 4 + lg) ^ (c & 7);
      b[nn] = *(const f16x8*)((const char*)W1s + c * 256 + (ch << 4));
    }
    #pragma unroll
    for (int m = 0; m < 4; ++m)
      #pragma unroll
      for (int nn = 0; nn < 4; ++nn)
        acc[m][nn] = __builtin_amdgcn_mfma_f32_16x16x32_f16(a[m], b[nn], acc[m][nn], 0, 0, 0);
  }

  // ---- relu+bias, h1 -> Az (swizzled), same layout as A ----
  {
    float b1v[4];
    #pragma unroll
    for (int nn = 0; nn < 4; ++nn) b1v[nn] = bias1[wc * 64 + nn * 16 + ls];
    __syncthreads();  // all phase-1 LDS reads complete
    #pragma unroll
    for (int m = 0; m < 4; ++m)
      #pragma unroll
      for (int nn = 0; nn < 4; ++nn)
        #pragma unroll
        for (int i = 0; i < 4; ++i) {
          int r = wr * 64 + m * 16 + lg * 4 + i;
          int c = wc * 64 + nn * 16 + ls;
          f16 v = (f16)fmaxf(acc[m][nn][i] + b1v[nn], 0.f);
          ((f16*)((char*)Az + r * 256 + ((((c >> 3) ^ (r & 7))) << 4)))[c & 7] = v;
        }
    __syncthreads();
  }

  // ---- phase 2: h2 = h1 @ W2 ----
  #pragma unroll
  for (int m = 0; m < 4; ++m)
    #pragma unroll
    for (int nn = 0; nn < 4; ++nn)
      acc[m][nn] = (f32x4){0.f, 0.f, 0.f, 0.f};
  #pragma unroll
  for (int ks = 0; ks < 4; ++ks) {
    f16x8 a[4], b[4];
    #pragma unroll
    for (int m = 0; m < 4; ++m) {
      int r = wr * 64 + m * 16 + ls;
      int ch = (ks * 4 + lg) ^ (r & 7);
      a[m] = *(const f16x8*)((const char*)Az + r * 256 + (ch << 4));
    }
    #pragma unroll
    for (int nn = 0; nn < 4; ++nn) {
      int c = wc * 64 + nn * 16 + ls;
      int ch = (ks * 4 + lg) ^ (c & 7);
      b[nn] = *(const f16x8*)((const char*)W2s + c * 256 + (ch << 4));
    }
    #pragma unroll
    for (int m = 0; m < 4; ++m)
      #pragma unroll
      for (int nn = 0; nn < 4; ++nn)
        acc[m][nn] = __builtin_amdgcn_mfma_f32_16x16x32_f16(a[m], b[nn], acc[m][nn], 0, 0, 0);
  }

  float b2v[4];
  #pragma unroll
  for (int nn = 0; nn < 4; ++nn) b2v[nn] = bias2[wc * 64 + nn * 16 + ls];

  if (FUSE) {
    float wv[4];
    #pragma unroll
    for (int nn = 0; nn < 4; ++nn) wv[nn] = wout[wc * 64 + nn * 16 + ls];
    float* red = (float*)W1s;  // [128][33] floats = 16.9KB, W1s dead after phase 1
    #pragma unroll
    for (int m = 0; m < 4; ++m)
      #pragma unroll
      for (int i = 0; i < 4; ++i) {
        int rl = wr * 64 + m * 16 + lg * 4 + i;
        float s = 0.f;
        #pragma unroll
        for (int nn = 0; nn < 4; ++nn)
          s += fmaxf(acc[m][nn][i] + b2v[nn], 0.f) * wv[nn];
        red[rl * 33 + wc * 16 + ls] = s;
      }
    __syncthreads();
    if (t < 128) {
      int gr = rowBase + t;
      if (gr < n) {
        float s = 0.f;
        #pragma unroll
        for (int g = 0; g < 32; ++g) s += red[t * 33 + g];
        ((float*)outv)[gr] = s + bout[0];
      }
    }
  } else {
    f16* out = (f16*)outv;
    #pragma unroll
    for (int m = 0; m < 4; ++m)
      #pragma unroll
      for (int i = 0; i < 4; ++i) {
        int gr = rowBase + wr * 64 + m * 16 + lg * 4 + i;
        if (gr < n) {
          f16* orow = out + (size_t)gr * 128 + wc * 64 + ls;
          #pragma unroll
          for (int nn = 0; nn < 4; ++nn)
            orow[nn * 16] = (f16)fmaxf(acc[m][nn][i] + b2v[nn], 0.f);
        }
      }
  }
}

// ---------------- launch ----------------

extern "C" void kernel_launch(void* const* d_in, const int* in_sizes, int n_in,
                              void* d_out, int out_size, void* d_ws, size_t ws_size,
                              hipStream_t stream) {
  const float* x = (const float*)d_in[0];
  const int* ei = (const int*)d_in[1];
  const float* w1[3] = {(const float*)d_in[2], (const float*)d_in[6], (const float*)d_in[10]};
  const float* b1[3] = {(const float*)d_in[3], (const float*)d_in[7], (const float*)d_in[11]};
  const float* w2[3] = {(const float*)d_in[4], (const float*)d_in[8], (const float*)d_in[12]};
  const float* b2[3] = {(const float*)d_in[5], (const float*)d_in[9], (const float*)d_in[13]};
  const float* wout = (const float*)d_in[14];
  const float* bout = (const float*)d_in[15];
  float* out = (float*)d_out;

  char* ws = (char*)d_ws;
  size_t off = 0;
  f16* B0  = (f16*)(ws + off); off += (size_t)N_NODES * 128 * 2;
  f16* B1  = (f16*)(ws + off); off += (size_t)N_NODES * 128 * 2;
  f16* x16 = (f16*)(ws + off); off += (size_t)N_NODES * 128 * 2;
  f16* Wt[6];
  for (int i = 0; i < 6; ++i) { Wt[i] = (f16*)(ws + off); off += 128 * 128 * 2; }
  int* offs   = (int*)(ws + off); off += (size_t)N_NODES * 4;
  int* counts = (int*)(ws + off); off += (size_t)N_NODES * 4;
  int* bsums  = (int*)(ws + off); off += 1024;
  int* srcs   = (int*)(ws + off); off += (size_t)N_EDGES * 4;
  int* rank   = (int*)(ws + off); off += (size_t)N_EDGES * 4;

  // ---- CSR build ----
  hipMemsetAsync(counts, 0, (size_t)N_NODES * 4, stream);
  hist_rank_kernel<<<(N_EDGES + 255) / 256, 256, 0, stream>>>(ei, counts, rank, N_EDGES);
  int nb = (N_NODES + 1023) / 1024;  // 98
  scan1_kernel<<<nb, 256, 0, stream>>>(counts, offs, bsums, N_NODES);
  scan2_kernel<<<1, 128, 0, stream>>>(bsums, nb);
  scan3_kernel<<<(N_NODES + 255) / 256, 256, 0, stream>>>(offs, bsums, N_NODES);
  int nchunks = (N_EDGES + FCHUNK - 1) / FCHUNK;  // 98
  fill_sliced_kernel<<<nchunks * 8, 256, 0, stream>>>(ei, offs, rank, srcs, N_EDGES);

  // ---- conversions ----
  cvt_kernel<<<(N_NODES * 128) / (256 * 8), 256, 0, stream>>>(x, x16);
  WPack wp;
  const float* wsrc[6] = {w1[0], w2[0], w1[1], w2[1], w1[2], w2[2]};
  for (int i = 0; i < 6; ++i) { wp.w[i] = wsrc[i]; wp.o[i] = Wt[i]; }
  wprep_all_kernel<<<384, 256, 0, stream>>>(wp);

  int aggGrid = (N_NODES * 64) / 256;    // 25000
  int lyrGrid = (N_NODES + 127) / 128;   // 782

  // layer 1
  aggregate_kernel<<<aggGrid, 256, 0, stream>>>(x16, offs, counts, srcs, B0, N_NODES);
  layer_kernel<0><<<lyrGrid, 256, 0, stream>>>(B0, Wt[0], Wt[1], b1[0], b2[0], B1, nullptr, nullptr, N_NODES);
  // layer 2
  aggregate_kernel<<<aggGrid, 256, 0, stream>>>(B1, offs, counts, srcs, B0, N_NODES);
  layer_kernel<0><<<lyrGrid, 256, 0, stream>>>(B0, Wt[2], Wt[3], b1[1], b2[1], B1, nullptr, nullptr, N_NODES);
  // layer 3 (+ fused w_out projection)
  aggregate_kernel<<<aggGrid, 256, 0, stream>>>(B1, offs, counts, srcs, B0, N_NODES);
  layer_kernel<1><<<lyrGrid, 256, 0, stream>>>(B0, Wt[4], Wt[5], b1[2], b2[2], out, wout, bout, N_NODES);
}

// Round 5
// 507.293 us; speedup vs baseline: 26.2237x; 1.0118x over previous
//
#include <hip/hip_runtime.h>

#define N_NODES 100000
#define N_EDGES 1600000
#define SLICE 12500     // N_NODES/8 dst-slice per group
#define FCHUNK 16384    // edges per fill chunk

typedef _Float16 f16;
typedef _Float16 f16x2 __attribute__((ext_vector_type(2)));
typedef _Float16 f16x4 __attribute__((ext_vector_type(4)));
typedef _Float16 f16x8 __attribute__((ext_vector_type(8)));
typedef float f32x4 __attribute__((ext_vector_type(4)));

// ---------------- CSR build ----------------
__global__ void hist_rank_kernel(const int* __restrict__ ei, int* __restrict__ counts,
                                 int* __restrict__ rank, int e) {
  int i = blockIdx.x * blockDim.x + threadIdx.x;
  if (i < e) rank[i] = atomicAdd(&counts[ei[e + i]], 1);
}

__global__ void scan1_kernel(const int* __restrict__ counts, int* __restrict__ offs,
                             int* __restrict__ bsums, int n) {
  __shared__ int sd[256];
  int t = threadIdx.x;
  int base = blockIdx.x * 1024 + t * 4;
  int v0 = (base + 0 < n) ? counts[base + 0] : 0;
  int v1 = (base + 1 < n) ? counts[base + 1] : 0;
  int v2 = (base + 2 < n) ? counts[base + 2] : 0;
  int v3 = (base + 3 < n) ? counts[base + 3] : 0;
  int s = v0 + v1 + v2 + v3;
  sd[t] = s;
  __syncthreads();
  for (int off = 1; off < 256; off <<= 1) {
    int x = (t >= off) ? sd[t - off] : 0;
    __syncthreads();
    sd[t] += x;
    __syncthreads();
  }
  int excl = sd[t] - s;
  if (t == 255) bsums[blockIdx.x] = sd[255];
  int r = excl;
  if (base + 0 < n) offs[base + 0] = r; r += v0;
  if (base + 1 < n) offs[base + 1] = r; r += v1;
  if (base + 2 < n) offs[base + 2] = r; r += v2;
  if (base + 3 < n) offs[base + 3] = r;
}

__global__ void scan2_kernel(int* __restrict__ bsums, int nb) {
  __shared__ int sd[128];
  int t = threadIdx.x;
  int v = (t < nb) ? bsums[t] : 0;
  sd[t] = v;
  __syncthreads();
  for (int off = 1; off < 128; off <<= 1) {
    int x = (t >= off) ? sd[t - off] : 0;
    __syncthreads();
    sd[t] += x;
    __syncthreads();
  }
  if (t < nb) bsums[t] = sd[t] - v;  // exclusive
}

__global__ void scan3_kernel(int* __restrict__ offs, const int* __restrict__ bsums, int n) {
  int i = blockIdx.x * blockDim.x + threadIdx.x;
  if (i < n) offs[i] += bsums[i >> 10];
}

__global__ void fill_sliced_kernel(const int* __restrict__ ei, const int* __restrict__ offs,
                                   const int* __restrict__ rank, int* __restrict__ srcs, int e) {
  int grp = blockIdx.x & 7;
  int chunk = blockIdx.x >> 3;
  int lo = grp * SLICE;
  int hi = lo + SLICE;
  int base = chunk * FCHUNK;
  #pragma unroll 4
  for (int k = threadIdx.x; k < FCHUNK; k += 256) {
    int i = base + k;
    if (i < e) {
      int d = ei[e + i];
      if (d >= lo && d < hi) srcs[offs[d] + rank[i]] = ei[i];
    }
  }
}

// ---------------- fp32 -> fp16 convert (x) ----------------
__global__ void cvt_kernel(const float* __restrict__ x, f16* __restrict__ y) {
  int i = (blockIdx.x * 256 + threadIdx.x) * 8;
  float4 a = *(const float4*)(x + i);
  float4 b = *(const float4*)(x + i + 4);
  f16x8 v = {(f16)a.x, (f16)a.y, (f16)a.z, (f16)a.w,
             (f16)b.x, (f16)b.y, (f16)b.z, (f16)b.w};
  *(f16x8*)(y + i) = v;
}

// ---------------- weight prep ----------------
// Wt[c*128 + kc*8 + j] = (f16)W[((kc ^ (c&7))*8 + j)*128 + c]
struct WPack { const float* w[6]; f16* o[6]; };
__global__ void wprep_all_kernel(WPack p) {
  int wi = blockIdx.x >> 6;
  int t = (blockIdx.x & 63) * 256 + threadIdx.x;
  int c = t >> 7;
  int i = t & 127;
  int kc = i >> 3, j = i & 7;
  int k = ((kc ^ (c & 7)) << 3) + j;
  p.o[wi][t] = (f16)p.w[wi][k * 128 + c];
}

// ---------------- aggregation: z[i] = h[i] + sum_{j in N_in(i)} h[j] ----------------
// 16-lane group per node: 16 lanes x f16x8 = full 256B row; 4 nodes per wave.
__global__ void aggregate_kernel(const f16* __restrict__ h, const int* __restrict__ offs,
                                 const int* __restrict__ deg, const int* __restrict__ srcs,
                                 f16* __restrict__ z, int n) {
  int gid = (int)((blockIdx.x * blockDim.x + threadIdx.x) >> 4);
  int gl = threadIdx.x & 15;
  int lb = threadIdx.x & 48;  // group base lane within wave
  if (gid >= n) return;
  int beg = offs[gid];
  int d = deg[gid];
  f16x8 hv = *(const f16x8*)(h + (size_t)gid * 128 + gl * 8);
  float acc[8];
  #pragma unroll
  for (int q = 0; q < 8; ++q) acc[q] = (float)hv[q];
  for (int base = 0; base < d; base += 16) {
    int cnt = min(16, d - base);
    int sv = (base + gl < d) ? srcs[beg + base + gl] : 0;
    int j = 0;
    for (; j + 2 <= cnt; j += 2) {
      int s0 = __shfl(sv, lb + j);
      int s1 = __shfl(sv, lb + j + 1);
      f16x8 a0 = *(const f16x8*)(h + (size_t)s0 * 128 + gl * 8);
      f16x8 a1 = *(const f16x8*)(h + (size_t)s1 * 128 + gl * 8);
      #pragma unroll
      for (int q = 0; q < 8; ++q) acc[q] += (float)a0[q] + (float)a1[q];
    }
    for (; j < cnt; ++j) {
      int s = __shfl(sv, lb + j);
      f16x8 a = *(const f16x8*)(h + (size_t)s * 128 + gl * 8);
      #pragma unroll
      for (int q = 0; q < 8; ++q) acc[q] += (float)a[q];
    }
  }
  f16x8 o;
  #pragma unroll
  for (int q = 0; q < 8; ++q) o[q] = (f16)acc[q];
  *(f16x8*)(z + (size_t)gid * 128 + gl * 8) = o;
}

// ---------------- fused GIN layer (swapped-MFMA): h2 = relu(relu(A@W1+b1)@W2+b2) ----------------
// Both phases compute the TRANSPOSED product via mfma(Wfrag, Afrag): D-fragment lane ls then
// holds h[row ...+ls][4 consecutive cols] -> packed ds_write_b64 writeback, coalesced stores.
// LDS: Az 32KB (A -> h1 -> h2) + Ws 32KB (W1 -> W2) = 64KB -> 2 blocks/CU.
template <int FUSE>
__global__ __launch_bounds__(256, 2)
void layer_kernel(const f16* __restrict__ A, const f16* __restrict__ W1t,
                  const f16* __restrict__ W2t,
                  const float* __restrict__ bias1, const float* __restrict__ bias2,
                  void* __restrict__ outv,
                  const float* __restrict__ wout, const float* __restrict__ bout, int n) {
  __shared__ f16 Az[128 * 128];  // 32KB
  __shared__ f16 Ws[128 * 128];  // 32KB
  const int t = threadIdx.x;
  const int lane = t & 63;
  const int w = t >> 6;
  const int rowBase = blockIdx.x * 128;
  const int wr = w >> 1, wc = w & 1;
  const int ls = lane & 15, lg = lane >> 4;

  // ---- stage A (swizzled) + W1 (linear; pre-swizzled in global) ----
  {
    const char* Ab = (const char*)(A + (size_t)rowBase * 128);
    float4 va[8], v1[8];
    #pragma unroll
    for (int i = 0; i < 8; ++i) {
      int s = w * 512 + i * 64 + lane;
      va[i] = *(const float4*)(Ab + s * 16);
      v1[i] = *(const float4*)((const char*)W1t + s * 16);
    }
    #pragma unroll
    for (int i = 0; i < 8; ++i) {
      int s = w * 512 + i * 64 + lane;
      int r = s >> 4, c = s & 15;
      *(float4*)((char*)Az + r * 256 + ((c ^ (r & 7)) << 4)) = va[i];
      *(float4*)((char*)Ws + s * 16) = v1[i];
    }
  }
  // prefetch W2 into regs (consumed after phase 1)
  float4 v2[8];
  #pragma unroll
  for (int i = 0; i < 8; ++i) {
    int s = w * 512 + i * 64 + lane;
    v2[i] = *(const float4*)((const char*)W2t + s * 16);
  }
  __syncthreads();

  f32x4 acc[4][4];
  #pragma unroll
  for (int m = 0; m < 4; ++m)
    #pragma unroll
    for (int nn = 0; nn < 4; ++nn)
      acc[m][nn] = (f32x4){0.f, 0.f, 0.f, 0.f};

  // ---- phase 1: acc[m][nn] = h1^T fragment ----
  // D rows (h1 cols) = wr*64+m*16+lg*4+i ; D cols (h1 rows) = wc*64+nn*16+ls
  #pragma unroll
  for (int ks = 0; ks < 4; ++ks) {
    f16x8 wf[4], af[4];
    #pragma unroll
    for (int m = 0; m < 4; ++m) {
      int c = wr * 64 + m * 16 + ls;
      int ch = (ks * 4 + lg) ^ (c & 7);
      wf[m] = *(const f16x8*)((const char*)Ws + c * 256 + (ch << 4));
    }
    #pragma unroll
    for (int nn = 0; nn < 4; ++nn) {
      int r = wc * 64 + nn * 16 + ls;
      int ch = (ks * 4 + lg) ^ (r & 7);
      af[nn] = *(const f16x8*)((const char*)Az + r * 256 + (ch << 4));
    }
    #pragma unroll
    for (int m = 0; m < 4; ++m)
      #pragma unroll
      for (int nn = 0; nn < 4; ++nn)
        acc[m][nn] = __builtin_amdgcn_mfma_f32_16x16x32_f16(wf[m], af[nn], acc[m][nn], 0, 0, 0);
  }
  __syncthreads();  // all phase-1 LDS reads complete

  // ---- W2 -> Ws ; h1 (relu+bias) -> Az as row-major packed b64 ----
  #pragma unroll
  for (int i = 0; i < 8; ++i) {
    int s = w * 512 + i * 64 + lane;
    *(float4*)((char*)Ws + s * 16) = v2[i];
  }
  #pragma unroll
  for (int m = 0; m < 4; ++m) {
    int c = wr * 64 + m * 16 + lg * 4;
    float b0 = bias1[c + 0], b1v = bias1[c + 1], b2v_ = bias1[c + 2], b3 = bias1[c + 3];
    #pragma unroll
    for (int nn = 0; nn < 4; ++nn) {
      int r = wc * 64 + nn * 16 + ls;
      f16x4 pv = {(f16)fmaxf(acc[m][nn][0] + b0, 0.f),
                  (f16)fmaxf(acc[m][nn][1] + b1v, 0.f),
                  (f16)fmaxf(acc[m][nn][2] + b2v_, 0.f),
                  (f16)fmaxf(acc[m][nn][3] + b3, 0.f)};
      *(f16x4*)((char*)Az + r * 256 + ((((c >> 3)) ^ (r & 7)) << 4) + (c & 7) * 2) = pv;
    }
  }
  __syncthreads();

  // ---- phase 2: acc[m][nn] = h2^T fragment (same structure) ----
  #pragma unroll
  for (int m = 0; m < 4; ++m)
    #pragma unroll
    for (int nn = 0; nn < 4; ++nn)
      acc[m][nn] = (f32x4){0.f, 0.f, 0.f, 0.f};
  #pragma unroll
  for (int ks = 0; ks < 4; ++ks) {
    f16x8 wf[4], hf[4];
    #pragma unroll
    for (int m = 0; m < 4; ++m) {
      int c = wr * 64 + m * 16 + ls;
      int ch = (ks * 4 + lg) ^ (c & 7);
      wf[m] = *(const f16x8*)((const char*)Ws + c * 256 + (ch << 4));
    }
    #pragma unroll
    for (int nn = 0; nn < 4; ++nn) {
      int r = wc * 64 + nn * 16 + ls;
      int ch = (ks * 4 + lg) ^ (r & 7);
      hf[nn] = *(const f16x8*)((const char*)Az + r * 256 + (ch << 4));
    }
    #pragma unroll
    for (int m = 0; m < 4; ++m)
      #pragma unroll
      for (int nn = 0; nn < 4; ++nn)
        acc[m][nn] = __builtin_amdgcn_mfma_f32_16x16x32_f16(wf[m], hf[nn], acc[m][nn], 0, 0, 0);
  }

  if (FUSE) {
    // lane holds h2[row wc*64+nn*16+ls][cols wr*64+m*16+lg*4+i]
    float s_[4] = {0.f, 0.f, 0.f, 0.f};
    #pragma unroll
    for (int m = 0; m < 4; ++m) {
      int c = wr * 64 + m * 16 + lg * 4;
      float bb[4], wv[4];
      #pragma unroll
      for (int i = 0; i < 4; ++i) { bb[i] = bias2[c + i]; wv[i] = wout[c + i]; }
      #pragma unroll
      for (int nn = 0; nn < 4; ++nn)
        #pragma unroll
        for (int i = 0; i < 4; ++i)
          s_[nn] += fmaxf(acc[m][nn][i] + bb[i], 0.f) * wv[i];
    }
    #pragma unroll
    for (int nn = 0; nn < 4; ++nn) {
      s_[nn] += __shfl_xor(s_[nn], 16);
      s_[nn] += __shfl_xor(s_[nn], 32);
    }
    __syncthreads();  // Az/Ws reads all complete
    float* red = (float*)Az;  // [128][2]
    if (lg == 0) {
      #pragma unroll
      for (int nn = 0; nn < 4; ++nn) red[(wc * 64 + nn * 16 + ls) * 2 + wr] = s_[nn];
    }
    __syncthreads();
    if (t < 128) {
      int gr = rowBase + t;
      if (gr < n) ((float*)outv)[gr] = red[t * 2] + red[t * 2 + 1] + bout[0];
    }
  } else {
    __syncthreads();  // phase-2 Az reads complete before overwrite
    #pragma unroll
    for (int m = 0; m < 4; ++m) {
      int c = wr * 64 + m * 16 + lg * 4;
      float b0 = bias2[c + 0], b1v = bias2[c + 1], b2v_ = bias2[c + 2], b3 = bias2[c + 3];
      #pragma unroll
      for (int nn = 0; nn < 4; ++nn) {
        int r = wc * 64 + nn * 16 + ls;
        f16x4 pv = {(f16)fmaxf(acc[m][nn][0] + b0, 0.f),
                    (f16)fmaxf(acc[m][nn][1] + b1v, 0.f),
                    (f16)fmaxf(acc[m][nn][2] + b2v_, 0.f),
                    (f16)fmaxf(acc[m][nn][3] + b3, 0.f)};
        *(f16x4*)((char*)Az + r * 256 + ((((c >> 3)) ^ (r & 7)) << 4) + (c & 7) * 2) = pv;
      }
    }
    __syncthreads();
    // coalesced store: 2 threads per row, 16B chunks (read back with same swizzle)
    f16* out = (f16*)outv;
    int r = t >> 1, half = t & 1;
    int gr = rowBase + r;
    if (gr < n) {
      #pragma unroll
      for (int j = 0; j < 8; ++j) {
        int ch = half * 8 + j;
        f16x8 v = *(const f16x8*)((const char*)Az + r * 256 + ((ch ^ (r & 7)) << 4));
        *(f16x8*)((char*)(out + (size_t)gr * 128) + half * 128 + j * 16) = v;
      }
    }
  }
}

// ---------------- launch ----------------

extern "C" void kernel_launch(void* const* d_in, const int* in_sizes, int n_in,
                              void* d_out, int out_size, void* d_ws, size_t ws_size,
                              hipStream_t stream) {
  const float* x = (const float*)d_in[0];
  const int* ei = (const int*)d_in[1];
  const float* w1[3] = {(const float*)d_in[2], (const float*)d_in[6], (const float*)d_in[10]};
  const float* b1[3] = {(const float*)d_in[3], (const float*)d_in[7], (const float*)d_in[11]};
  const float* w2[3] = {(const float*)d_in[4], (const float*)d_in[8], (const float*)d_in[12]};
  const float* b2[3] = {(const float*)d_in[5], (const float*)d_in[9], (const float*)d_in[13]};
  const float* wout = (const float*)d_in[14];
  const float* bout = (const float*)d_in[15];
  float* out = (float*)d_out;

  char* ws = (char*)d_ws;
  size_t off = 0;
  f16* B0  = (f16*)(ws + off); off += (size_t)N_NODES * 128 * 2;
  f16* B1  = (f16*)(ws + off); off += (size_t)N_NODES * 128 * 2;
  f16* x16 = (f16*)(ws + off); off += (size_t)N_NODES * 128 * 2;
  f16* Wt[6];
  for (int i = 0; i < 6; ++i) { Wt[i] = (f16*)(ws + off); off += 128 * 128 * 2; }
  int* offs   = (int*)(ws + off); off += (size_t)N_NODES * 4;
  int* counts = (int*)(ws + off); off += (size_t)N_NODES * 4;
  int* bsums  = (int*)(ws + off); off += 1024;
  int* srcs   = (int*)(ws + off); off += (size_t)N_EDGES * 4;
  int* rank   = (int*)(ws + off); off += (size_t)N_EDGES * 4;

  // ---- CSR build ----
  hipMemsetAsync(counts, 0, (size_t)N_NODES * 4, stream);
  hist_rank_kernel<<<(N_EDGES + 255) / 256, 256, 0, stream>>>(ei, counts, rank, N_EDGES);
  int nb = (N_NODES + 1023) / 1024;
  scan1_kernel<<<nb, 256, 0, stream>>>(counts, offs, bsums, N_NODES);
  scan2_kernel<<<1, 128, 0, stream>>>(bsums, nb);
  scan3_kernel<<<(N_NODES + 255) / 256, 256, 0, stream>>>(offs, bsums, N_NODES);
  int nchunks = (N_EDGES + FCHUNK - 1) / FCHUNK;
  fill_sliced_kernel<<<nchunks * 8, 256, 0, stream>>>(ei, offs, rank, srcs, N_EDGES);

  // ---- conversions ----
  cvt_kernel<<<(N_NODES * 128) / (256 * 8), 256, 0, stream>>>(x, x16);
  WPack wp;
  const float* wsrc[6] = {w1[0], w2[0], w1[1], w2[1], w1[2], w2[2]};
  for (int i = 0; i < 6; ++i) { wp.w[i] = wsrc[i]; wp.o[i] = Wt[i]; }
  wprep_all_kernel<<<384, 256, 0, stream>>>(wp);

  int aggGrid = (N_NODES * 16) / 256;    // 6250 (16-lane group per node)
  int lyrGrid = (N_NODES + 127) / 128;   // 782

  // layer 1
  aggregate_kernel<<<aggGrid, 256, 0, stream>>>(x16, offs, counts, srcs, B0, N_NODES);
  layer_kernel<0><<<lyrGrid, 256, 0, stream>>>(B0, Wt[0], Wt[1], b1[0], b2[0], B1, nullptr, nullptr, N_NODES);
  // layer 2
  aggregate_kernel<<<aggGrid, 256, 0, stream>>>(B1, offs, counts, srcs, B0, N_NODES);
  layer_kernel<0><<<lyrGrid, 256, 0, stream>>>(B0, Wt[2], Wt[3], b1[1], b2[1], B1, nullptr, nullptr, N_NODES);
  // layer 3 (+ fused w_out projection)
  aggregate_kernel<<<aggGrid, 256, 0, stream>>>(B1, offs, counts, srcs, B0, N_NODES);
  layer_kernel<1><<<lyrGrid, 256, 0, stream>>>(B0, Wt[4], Wt[5], b1[2], b2[2], out, wout, bout, N_NODES);
}